// Round 22
// baseline (157.464 us; speedup 1.0000x reference)
//
#include <hip/hip_runtime.h>
#include <hip/hip_bf16.h>
#include <math.h>

#define B_SZ   2
#define S_LEN  2048
#define C_DIM  1280
#define H_NUM  20
#define D_HEAD 64
#define M_TOT  (B_SZ * S_LEN)          // 4096

typedef __bf16 bf16;
typedef __bf16 bf16x8 __attribute__((ext_vector_type(8)));
typedef __bf16 bf16x4 __attribute__((ext_vector_type(4)));
typedef float  f32x4  __attribute__((ext_vector_type(4)));

__device__ inline f32x4 zero4() { f32x4 z; z[0]=z[1]=z[2]=z[3]=0.f; return z; }

// async global->LDS, 16B per lane. LDS dest must be wave-uniform base + lane*16.
__device__ __forceinline__ void async_copy16(void* lds, const void* g) {
    __builtin_amdgcn_global_load_lds(
        (const __attribute__((address_space(1))) unsigned int*)g,
        (__attribute__((address_space(3))) unsigned int*)lds,
        16, 0, 0);
}

// ---------------- fused preprocessing: hs fp32->bf16 + 4x W transpose ----------------
__global__ __launch_bounds__(256) void k_prep(
    const float* __restrict__ hs, bf16* __restrict__ hs_bf,
    const float* __restrict__ w0, const float* __restrict__ w1,
    const float* __restrict__ w2, const float* __restrict__ w3,
    bf16* __restrict__ o0, bf16* __restrict__ o1,
    bf16* __restrict__ o2, bf16* __restrict__ o3) {
    if (blockIdx.x < 5120) {
        int i = (blockIdx.x * 256 + threadIdx.x) * 4;
        float4 v = *(const float4*)(hs + i);
        bf16x4 o; o[0]=(bf16)v.x; o[1]=(bf16)v.y; o[2]=(bf16)v.z; o[3]=(bf16)v.w;
        *(bf16x4*)(hs_bf + i) = o;
        return;
    }
    __shared__ float t[32][33];
    int idx = blockIdx.x - 5120;
    int zi  = idx / 1600;
    int rem = idx % 1600;
    int k0 = (rem / 40) * 32, n0 = (rem % 40) * 32;
    const float* w = zi==0 ? w0 : zi==1 ? w1 : zi==2 ? w2 : w3;
    bf16*       o  = zi==0 ? o0 : zi==1 ? o1 : zi==2 ? o2 : o3;
    int tx = threadIdx.x & 31, ty = threadIdx.x >> 5;   // 32 x 8
    #pragma unroll
    for (int i = 0; i < 32; i += 8)
        t[ty+i][tx] = w[(size_t)(k0+ty+i)*C_DIM + n0 + tx];
    __syncthreads();
    #pragma unroll
    for (int i = 0; i < 32; i += 8)
        o[(size_t)(n0+ty+i)*C_DIM + k0 + tx] = (bf16)t[tx][ty+i];
}

// ------------- Fused QKV GEMM: 256x256 tile, BK=32, triple-buffered LDS,
// raw s_barrier + counted vmcnt, XOR-granule swizzle (R21). -------------
#define QBM 256
#define QBN 256
#define QBK 32
#define QNT (C_DIM / QBK)   // 40
__global__ __launch_bounds__(512, 2) void k_gemm_qkv(
    const bf16* __restrict__ A,      // hs_bf [4096][1280]
    const bf16* __restrict__ Wcat,   // [3840][1280] = WqT|WkT|WvT
    bf16* __restrict__ Qo, bf16* __restrict__ Ko, bf16* __restrict__ VTo) {
    __shared__ bf16 lds[3][2][QBM][QBK];   // 96 KB
    const int m0  = blockIdx.y * QBM;
    const int nx  = blockIdx.x;            // 0..14
    const int z   = nx / 5;                // which weight
    const int nw0 = (nx % 5) * QBN;        // within-weight col base
    const int ng0 = nx * QBN;              // row into Wcat
    const int tid = threadIdx.x, lane = tid & 63, wid = tid >> 6;
    const int wm = wid >> 2, wn = wid & 3;
    const int g = lane >> 4, lr = lane & 15;
    const float scale = (z==0) ? 0.18033688011112042f : 1.0f;  // log2e/8 for Q

    f32x4 acc[8][4];
    #pragma unroll
    for (int i=0;i<8;i++)
        #pragma unroll
        for (int j=0;j<4;j++)
            acc[i][j] = zero4();

#define QSTAGE(bf, kt)                                                       \
    { const int k0_ = (kt)*QBK;                                              \
      _Pragma("unroll")                                                      \
      for (int c = 0; c < 2; ++c) {                                          \
        int p = c*512 + tid;                                                 \
        int row = p >> 2, gp = p & 3, gc = gp ^ ((row >> 1) & 3);            \
        async_copy16((char*)&lds[bf][0][0][0] + p*16,                        \
                     &A[(size_t)(m0+row)*C_DIM + k0_ + gc*8]);               \
        async_copy16((char*)&lds[bf][1][0][0] + p*16,                        \
                     &Wcat[(size_t)(ng0+row)*C_DIM + k0_ + gc*8]);           \
      } }

    QSTAGE(0, 0);
    QSTAGE(1, 1);
    asm volatile("s_waitcnt vmcnt(4)" ::: "memory");
    __builtin_amdgcn_s_barrier();

    int cur = 0;
    for (int t = 0; t < QNT; ++t) {
        if (t + 2 < QNT) {
            int sb = cur + 2; if (sb >= 3) sb -= 3;
            QSTAGE(sb, t + 2);
        }
        const bf16* AB = &lds[cur][0][0][0];
        const bf16* BB = &lds[cur][1][0][0];
        bf16x8 af[8], bfr[4];
        #pragma unroll
        for (int mf = 0; mf < 8; ++mf) {
            int arow = wm*128 + mf*16 + lr;
            af[mf] = *(const bf16x8*)(AB + arow*QBK + ((g ^ ((arow >> 1) & 3)) << 3));
        }
        #pragma unroll
        for (int nf = 0; nf < 4; ++nf) {
            int brow = wn*64 + nf*16 + lr;
            bfr[nf] = *(const bf16x8*)(BB + brow*QBK + ((g ^ ((brow >> 1) & 3)) << 3));
        }
        #pragma unroll
        for (int mf = 0; mf < 8; ++mf)
            #pragma unroll
            for (int nf = 0; nf < 4; ++nf)
                acc[mf][nf] = __builtin_amdgcn_mfma_f32_16x16x32_bf16(
                    af[mf], bfr[nf], acc[mf][nf], 0,0,0);
        if (t + 2 < QNT) asm volatile("s_waitcnt vmcnt(4) lgkmcnt(0)" ::: "memory");
        else             asm volatile("s_waitcnt vmcnt(0) lgkmcnt(0)" ::: "memory");
        __builtin_amdgcn_s_barrier();
        if (++cur == 3) cur = 0;
    }

    if (z == 2) {
        #pragma unroll
        for (int mf=0;mf<8;mf++) {
            #pragma unroll
            for (int nf=0;nf<4;nf++) {
                int n = nw0 + wn*64 + nf*16 + lr;
                int h = n >> 6, d = n & 63;
                int m = m0 + wm*128 + mf*16 + g*4;
                int b = m >> 11, s = m & (S_LEN-1);
                bf16x4 ov;
                #pragma unroll
                for (int r=0;r<4;r++) ov[r] = (bf16)acc[mf][nf][r];
                *(bf16x4*)&VTo[((size_t)(b*H_NUM + h)*D_HEAD + d)*S_LEN + s] = ov;
            }
        }
    } else {
        bf16* Out = (z==0) ? Qo : Ko;
        #pragma unroll
        for (int mf=0;mf<8;mf++) {
            #pragma unroll
            for (int nf=0;nf<4;nf++) {
                int n = nw0 + wn*64 + nf*16 + lr;
                int h = n >> 6, d = n & 63;
                #pragma unroll
                for (int r=0;r<4;r++) {
                    int m = m0 + wm*128 + mf*16 + g*4 + r;
                    int b = m >> 11, s = m & (S_LEN-1);
                    Out[(size_t)((b*H_NUM + h)*S_LEN + s)*D_HEAD + d] = (bf16)(acc[mf][nf][r] * scale);
                }
            }
        }
    }
}

// ------------- output GEMM (128x128, BK=64, swizzled, dbuf early-issue)
// + folded deterministic loss reduce (block (0,0) only). -------------
#define BM 128
#define BN 128
#define BK 64

#define GEMM_STAGE(Al, Bl, Aptr, Bptr, m0, n0, k0)                                \
    {                                                                             \
        _Pragma("unroll")                                                         \
        for (int c = 0; c < 4; ++c) {                                             \
            int p = c*256 + tid;                                                  \
            int row = p >> 3, gp = p & 7, gc = gp ^ (row & 7);                    \
            async_copy16((char*)(Al) + p*16,                                      \
                         &Aptr[(size_t)((m0)+row)*C_DIM + (k0) + gc*8]);          \
            async_copy16((char*)(Bl) + p*16,                                      \
                         &Bptr[(size_t)((n0)+row)*C_DIM + (k0) + gc*8]);          \
        }                                                                         \
    }

#define GEMM_COMPUTE(Al, Bl)                                                      \
    {                                                                             \
        _Pragma("unroll")                                                         \
        for (int kk = 0; kk < 2; ++kk) {                                          \
            bf16x8 af[4], bfr[4];                                                 \
            _Pragma("unroll")                                                     \
            for (int mf = 0; mf < 4; ++mf) {                                      \
                int arow = wm*64 + mf*16 + lr;                                    \
                af[mf] = *(const bf16x8*)((char*)(Al) + arow*128 +                \
                          (((kk*4 + g) ^ (arow & 7)) << 4));                      \
            }                                                                     \
            _Pragma("unroll")                                                     \
            for (int nf = 0; nf < 4; ++nf) {                                      \
                int brow = wn*64 + nf*16 + lr;                                    \
                bfr[nf] = *(const bf16x8*)((char*)(Bl) + brow*128 +               \
                          (((kk*4 + g) ^ (brow & 7)) << 4));                      \
            }                                                                     \
            _Pragma("unroll")                                                     \
            for (int mf = 0; mf < 4; ++mf)                                        \
                _Pragma("unroll")                                                 \
                for (int nf = 0; nf < 4; ++nf)                                    \
                    acc[mf][nf] = __builtin_amdgcn_mfma_f32_16x16x32_bf16(        \
                        af[mf], bfr[nf], acc[mf][nf], 0,0,0);                     \
        }                                                                         \
    }

__global__ __launch_bounds__(256) void k_gemm_out(
    const bf16* __restrict__ A,                     // combined Oattn [4096][1280]
    const bf16* __restrict__ WoT,
    const float* __restrict__ bo,
    const float* __restrict__ res,                  // hidden_states fp32
    float* __restrict__ out,
    const float* __restrict__ lossPart, int nLoss) {
    __shared__ bf16 Al[2][BM][BK];
    __shared__ bf16 Bl[2][BN][BK];
    __shared__ float wred[4];
    const int m0 = blockIdx.y * BM, n0 = blockIdx.x * BN;
    const int tid = threadIdx.x, lane = tid & 63, wid = tid >> 6;
    const int wm = wid >> 1, wn = wid & 1;
    const int g = lane >> 4, lr = lane & 15;
    f32x4 acc[4][4];
    #pragma unroll
    for (int i=0;i<4;i++)
        #pragma unroll
        for (int j=0;j<4;j++)
            acc[i][j] = zero4();
    GEMM_STAGE(&Al[0][0][0], &Bl[0][0][0], A, WoT, m0, n0, 0);
    asm volatile("s_waitcnt vmcnt(0)" ::: "memory");
    __builtin_amdgcn_s_barrier();
    int cur = 0;
    for (int k0 = 0; k0 < C_DIM; k0 += BK) {
        if (k0 + BK < C_DIM)
            GEMM_STAGE(&Al[cur^1][0][0], &Bl[cur^1][0][0], A, WoT, m0, n0, k0 + BK);
        GEMM_COMPUTE(&Al[cur][0][0], &Bl[cur][0][0]);
        asm volatile("s_waitcnt vmcnt(0) lgkmcnt(0)" ::: "memory");
        __builtin_amdgcn_s_barrier();
        cur ^= 1;
    }
    #pragma unroll
    for (int mf=0;mf<4;mf++) {
        #pragma unroll
        for (int nf=0;nf<4;nf++) {
            int n = n0 + wn*64 + nf*16 + lr;
            float bias = bo[n];
            #pragma unroll
            for (int r=0;r<4;r++) {
                int m = m0 + wm*64 + mf*16 + g*4 + r;
                size_t idx = (size_t)m*C_DIM + n;
                out[idx] = acc[mf][nf][r] + bias + res[idx];
            }
        }
    }
    if (blockIdx.x == 0 && blockIdx.y == 0) {
        float s = 0.f;
        for (int i = tid; i < nLoss; i += 256) s += lossPart[i];
        #pragma unroll
        for (int msk=1; msk<64; msk<<=1) s += __shfl_xor(s, msk);
        if (lane == 0) wred[wid] = s;
        __syncthreads();
        if (tid == 0) out[(size_t)M_TOT*C_DIM] = sqrtf(wred[0]+wred[1]+wred[2]+wred[3]);
    }
}

// ------------- flash attention, KV-SPLIT x2 + 2 q-strips/wave -------------
// Each block: 256 q rows (8 waves x 32 q) over HALF the KV range (16 tiles).
// LDS-read amplification halves (attn was DS-BW-bound: every wave reads the
// whole K/V tile). Grid stays 640 = 320 (bh,qb) x 2 halves -> occupancy kept.
// Unnormalized softmax is max-free => halves combine exactly:
// O = (O0+O1)/(l0+l1). Partials: half0->O0buf, half1->O1buf (bf16, unnorm);
// l & s2 per q to f32 bufs. Triple-buffered K/V + counted vmcnt (R18).
#define KVB 64
#define HTILES (S_LEN / KVB / 2)   // 16
__global__ __launch_bounds__(512) void k_attn(
    const bf16* __restrict__ Q,    // [B,H,S,D], pre-scaled by log2e/8
    const bf16* __restrict__ Kg,   // [B,H,S,D]
    const bf16* __restrict__ VT,   // [B,H,D,S]
    bf16* __restrict__ O0buf,      // [B,S,H,D] unnorm partial, half 0
    bf16* __restrict__ O1buf,      // [B,S,H,D] unnorm partial, half 1
    float* __restrict__ lbuf,      // [2][40][2048]
    float* __restrict__ s2buf) {   // [2][40][2048]
    __shared__ bf16 Kl[3][KVB][64];
    __shared__ bf16 Vl[3][D_HEAD][64];   // 48 KB

    const int id  = blockIdx.x;              // 0..639
    const int fid = (id & 7) * 80 + (id >> 3);   // XCD-contiguous (640%8==0)
    const int bh   = fid >> 4;               // 0..39 (5 whole heads per XCD)
    const int rem  = fid & 15;
    const int qb   = rem >> 1;               // 0..7 (256 q rows per block)
    const int half = rem & 1;                // KV half
    const int b = bh / H_NUM, hh = bh % H_NUM;
    const int tid = threadIdx.x, lane = tid & 63, wid = tid >> 6;  // wid 0..7
    const int g = lane >> 4, lr = lane & 15;
    const int kvbase = half * (S_LEN/2);

    const bf16* Kbase = Kg + (size_t)bh * S_LEN * D_HEAD;
    const bf16* Vbase = VT + (size_t)bh * D_HEAD * S_LEN;

    // per-lane q rows: strip h at qb*256 + wid*32 + h*16 + lr
    bf16x8 aq[2][2];
    int qrow[2];
    #pragma unroll
    for (int h=0; h<2; ++h) {
        qrow[h] = qb*256 + wid*32 + h*16 + lr;
        const bf16* qp = Q + ((size_t)bh*S_LEN + qrow[h])*D_HEAD;
        aq[h][0] = *(const bf16x8*)(qp + g*8);
        aq[h][1] = *(const bf16x8*)(qp + 32 + g*8);
    }

    bf16x8 ones;
    #pragma unroll
    for (int i=0;i<8;i++) ones[i] = (bf16)1.0f;

    // K LDS read-row components (phys kv -> LDS row sigma: swap bits 2,3)
    const int lb7 = (lr & 3) | (((lr >> 2) & 1) << 2);
    const int lhi = ((lr >> 2) & 2) << 3;

    f32x4 o_acc[2][4];
    f32x4 l_acc[2], s2m[2];
    #pragma unroll
    for (int h=0;h<2;++h) {
        #pragma unroll
        for (int i=0;i<4;i++) o_acc[h][i] = zero4();
        l_acc[h] = zero4(); s2m[h] = zero4();
    }

// 512 threads cover the 512 K granules (and 512 V granules): 2 vmem ops/thread.
#define STAGE(buf, kv0)                                                          \
    {                                                                            \
        {                                                                        \
            int p = tid;                                                         \
            int lrow = p >> 3, gp = p & 7;                                       \
            int tl = (lrow & 51) | ((lrow & 4) << 1) | ((lrow & 8) >> 1);        \
            async_copy16((char*)&Kl[buf][0][0] + p*16,                           \
                         Kbase + (size_t)((kv0) + tl)*D_HEAD                     \
                               + ((gp ^ (lrow & 7)) << 3));                      \
        }                                                                        \
        {                                                                        \
            int p = tid;                                                         \
            int drow = p >> 3, gp = p & 7;                                       \
            async_copy16((char*)&Vl[buf][0][0] + p*16,                           \
                         Vbase + (size_t)drow*S_LEN + (kv0)                      \
                               + ((gp ^ (drow & 7)) << 3));                      \
        }                                                                        \
    }

    STAGE(0, kvbase);
    STAGE(1, kvbase + KVB);
    asm volatile("s_waitcnt vmcnt(2)" ::: "memory");
    __builtin_amdgcn_s_barrier();

    int cur = 0;
    for (int t = 0; t < HTILES; ++t) {
        if (t + 2 < HTILES) {
            int sb = cur + 2; if (sb >= 3) sb -= 3;
            STAGE(sb, kvbase + (t+2)*KVB);
        }
        const bf16* KB = &Kl[cur][0][0];
        const bf16* VB = &Vl[cur][0][0];

        // QK^T (swapped): K fragments shared by both strips
        f32x4 accp[2][2][2];   // [h][pair][u]
        __builtin_amdgcn_s_setprio(1);
        #pragma unroll
        for (int pair=0; pair<2; ++pair)
            #pragma unroll
            for (int u=0; u<2; ++u) {
                const bf16* kr = KB + (pair*32 + (u<<3) + lhi + lb7)*64;
                bf16x8 k0 = *(const bf16x8*)(kr + ((g       ^ lb7) << 3));
                bf16x8 k1 = *(const bf16x8*)(kr + (((4 + g) ^ lb7) << 3));
                #pragma unroll
                for (int h=0; h<2; ++h) {
                    f32x4 c = zero4();
                    c = __builtin_amdgcn_mfma_f32_16x16x32_bf16(k0, aq[h][0], c, 0,0,0);
                    c = __builtin_amdgcn_mfma_f32_16x16x32_bf16(k1, aq[h][1], c, 0,0,0);
                    accp[h][pair][u] = c;
                }
            }
        __builtin_amdgcn_s_setprio(0);
        // unnormalized p = 2^(s'): single v_exp_f32 each, lane-local
        bf16x8 pb[2][2];
        #pragma unroll
        for (int h=0; h<2; ++h)
            #pragma unroll
            for (int pair=0; pair<2; ++pair)
                #pragma unroll
                for (int u=0; u<2; ++u)
                    #pragma unroll
                    for (int r=0; r<4; ++r) {
                        float e = __builtin_amdgcn_exp2f(accp[h][pair][u][r]);
                        pb[h][pair][u*4+r] = (bf16)e;
                    }
        __builtin_amdgcn_s_setprio(1);
        // l and s2 via MFMA (fully k-reduced per q column)
        #pragma unroll
        for (int h=0; h<2; ++h) {
            l_acc[h] = __builtin_amdgcn_mfma_f32_16x16x32_bf16(ones, pb[h][0], l_acc[h], 0,0,0);
            l_acc[h] = __builtin_amdgcn_mfma_f32_16x16x32_bf16(ones, pb[h][1], l_acc[h], 0,0,0);
            s2m[h]   = __builtin_amdgcn_mfma_f32_16x16x32_bf16(pb[h][0], pb[h][0], s2m[h], 0,0,0);
            s2m[h]   = __builtin_amdgcn_mfma_f32_16x16x32_bf16(pb[h][1], pb[h][1], s2m[h], 0,0,0);
        }
        // PV: V fragments shared by both strips
        #pragma unroll
        for (int ds_=0; ds_<4; ++ds_) {
            const bf16* vr = VB + (ds_*16 + lr)*64;
            #pragma unroll
            for (int pair=0; pair<2; ++pair) {
                bf16x8 v = *(const bf16x8*)(vr + (((pair*4 + g) ^ (lr & 7)) << 3));
                #pragma unroll
                for (int h=0; h<2; ++h)
                    o_acc[h][ds_] = __builtin_amdgcn_mfma_f32_16x16x32_bf16(v, pb[h][pair], o_acc[h][ds_], 0,0,0);
            }
        }
        __builtin_amdgcn_s_setprio(0);
        if (t + 2 < HTILES) asm volatile("s_waitcnt vmcnt(2) lgkmcnt(0)" ::: "memory");
        else                asm volatile("s_waitcnt vmcnt(0) lgkmcnt(0)" ::: "memory");
        __builtin_amdgcn_s_barrier();
        if (++cur == 3) cur = 0;
    }

    // partial writes (UNNORMALIZED): O to half-specific buffer; l/s2 per q.
    bf16* Od = half ? O1buf : O0buf;
    #pragma unroll
    for (int h=0; h<2; ++h) {
        bf16* orow = Od + ((size_t)(b*S_LEN + qrow[h])*H_NUM + hh)*D_HEAD;
        #pragma unroll
        for (int ds_=0; ds_<4; ++ds_) {
            bf16x4 ov;
            #pragma unroll
            for (int r=0; r<4; ++r) ov[r] = (bf16)(o_acc[h][ds_][r]);
            *(bf16x4*)(orow + ds_*16 + g*4) = ov;
        }
        // l: every lane holds l of its col q=lr (all rows equal); g==0 lanes write.
        size_t base = (size_t)half*(40*2048) + (size_t)bh*2048 + qrow[h];
        if (g == 0) lbuf[base] = l_acc[h][0];
        // s2 diag for q=lr sits on lane g==lr>>2, element lr&3.
        if (g == (lr >> 2)) s2buf[base] = s2m[h][lr & 3];
    }
}

// ------------- combine halves (in-place into O0) + loss partials -------------
__global__ __launch_bounds__(256) void k_combine(
    bf16* __restrict__ O0, const bf16* __restrict__ O1,
    const float* __restrict__ lbuf, const float* __restrict__ s2buf,
    float* __restrict__ lossPart) {
    __shared__ float wred[4];
    const int tid = threadIdx.x, lane = tid & 63, wid = tid >> 6;
    if (blockIdx.x < 2560) {
        size_t e = (size_t)blockIdx.x * 2048 + (size_t)tid * 8;
        int sg = (int)(e / C_DIM), c = (int)(e % C_DIM);
        int b = sg >> 11, s = sg & (S_LEN-1), h = c >> 6;
        size_t lb = (size_t)(b*H_NUM + h)*2048 + s;
        float inv = 1.0f / (lbuf[lb] + lbuf[40*2048 + lb]);
        bf16x8 a = *(const bf16x8*)(O0 + e);
        bf16x8 bb = *(const bf16x8*)(O1 + e);
        bf16x8 o;
        #pragma unroll
        for (int j=0;j<8;j++) o[j] = (bf16)(((float)a[j] + (float)bb[j]) * inv);
        *(bf16x8*)(O0 + e) = o;
        return;
    }
    // loss blocks: one per bh
    int bh = blockIdx.x - 2560;   // 0..39
    float v = 0.f;
    for (int s = tid; s < 2048; s += 256) {
        size_t lb = (size_t)bh*2048 + s;
        float l  = lbuf[lb]  + lbuf[40*2048 + lb];
        float s2 = s2buf[lb] + s2buf[40*2048 + lb];
        v += s2 / (l*l);
    }
    #pragma unroll
    for (int msk=1; msk<64; msk<<=1) v += __shfl_xor(v, msk);
    if (lane == 0) wred[wid] = v;
    __syncthreads();
    if (tid == 0) lossPart[bh] = wred[0]+wred[1]+wred[2]+wred[3];
}

extern "C" void kernel_launch(void* const* d_in, const int* in_sizes, int n_in,
                              void* d_out, int out_size, void* d_ws, size_t ws_size,
                              hipStream_t stream) {
    (void)in_sizes; (void)n_in; (void)out_size; (void)ws_size;
    const float* hs = (const float*)d_in[0];
    const float* Wq = (const float*)d_in[1];
    const float* Wk = (const float*)d_in[2];
    const float* Wv = (const float*)d_in[3];
    const float* Wo = (const float*)d_in[4];
    const float* bo = (const float*)d_in[5];
    float* out = (float*)d_out;

    constexpr size_t HS_E = (size_t)M_TOT * C_DIM;       // 5,242,880
    constexpr size_t W_E  = (size_t)C_DIM * C_DIM;       // 1,638,400
    char* ws = (char*)d_ws;
    size_t off = 0;
    bf16* hs_bf = (bf16*)(ws + off); off += HS_E * 2;    // later reused as O1 partial
    bf16* WqT   = (bf16*)(ws + off); off += W_E * 2;     // WqT|WkT|WvT contiguous
    bf16* WkT   = (bf16*)(ws + off); off += W_E * 2;
    bf16* WvT   = (bf16*)(ws + off); off += W_E * 2;
    bf16* WoT   = (bf16*)(ws + off); off += W_E * 2;
    bf16* Qb    = (bf16*)(ws + off); off += HS_E * 2;
    bf16* Kb    = (bf16*)(ws + off); off += HS_E * 2;
    bf16* Vtb   = (bf16*)(ws + off); off += HS_E * 2;    // V^T [B,H,D,S], written by gemm
    bf16* Ob    = (bf16*)(ws + off); off += HS_E * 2;    // O partial half 0 -> combined
    float* lbuf  = (float*)(ws + off); off += 2 * 40 * 2048 * 4;
    float* s2buf = (float*)(ws + off); off += 2 * 40 * 2048 * 4;
    float* lossPart = (float*)(ws + off); off += 40 * 4;

    k_prep<<<11520, 256, 0, stream>>>(hs, hs_bf, Wq, Wk, Wv, Wo, WqT, WkT, WvT, WoT);
    k_gemm_qkv<<<dim3(3*C_DIM/QBN, M_TOT/QBM), 512, 0, stream>>>(hs_bf, WqT, Qb, Kb, Vtb);
    // hs_bf is dead after QKV -> reuse as the half-1 O partial buffer
    k_attn<<<640, 512, 0, stream>>>(Qb, Kb, Vtb, Ob, hs_bf, lbuf, s2buf);
    k_combine<<<2600, 256, 0, stream>>>(Ob, hs_bf, lbuf, s2buf, lossPart);
    k_gemm_out<<<dim3(C_DIM/BN, M_TOT/BM), 256, 0, stream>>>(Ob, WoT, bo, hs, out, lossPart, 40);
}

// Round 23
// 152.317 us; speedup vs baseline: 1.0338x; 1.0338x over previous
//
#include <hip/hip_runtime.h>
#include <hip/hip_bf16.h>
#include <math.h>

#define B_SZ   2
#define S_LEN  2048
#define C_DIM  1280
#define H_NUM  20
#define D_HEAD 64
#define M_TOT  (B_SZ * S_LEN)          // 4096

typedef __bf16 bf16;
typedef __bf16 bf16x8 __attribute__((ext_vector_type(8)));
typedef __bf16 bf16x4 __attribute__((ext_vector_type(4)));
typedef float  f32x4  __attribute__((ext_vector_type(4)));

__device__ inline f32x4 zero4() { f32x4 z; z[0]=z[1]=z[2]=z[3]=0.f; return z; }

// async global->LDS, 16B per lane. LDS dest must be wave-uniform base + lane*16.
__device__ __forceinline__ void async_copy16(void* lds, const void* g) {
    __builtin_amdgcn_global_load_lds(
        (const __attribute__((address_space(1))) unsigned int*)g,
        (__attribute__((address_space(3))) unsigned int*)lds,
        16, 0, 0);
}

// ---------------- fused preprocessing: hs fp32->bf16 + 4x W transpose ----------------
__global__ __launch_bounds__(256) void k_prep(
    const float* __restrict__ hs, bf16* __restrict__ hs_bf,
    const float* __restrict__ w0, const float* __restrict__ w1,
    const float* __restrict__ w2, const float* __restrict__ w3,
    bf16* __restrict__ o0, bf16* __restrict__ o1,
    bf16* __restrict__ o2, bf16* __restrict__ o3) {
    if (blockIdx.x < 5120) {
        int i = (blockIdx.x * 256 + threadIdx.x) * 4;
        float4 v = *(const float4*)(hs + i);
        bf16x4 o; o[0]=(bf16)v.x; o[1]=(bf16)v.y; o[2]=(bf16)v.z; o[3]=(bf16)v.w;
        *(bf16x4*)(hs_bf + i) = o;
        return;
    }
    __shared__ float t[32][33];
    int idx = blockIdx.x - 5120;
    int zi  = idx / 1600;
    int rem = idx % 1600;
    int k0 = (rem / 40) * 32, n0 = (rem % 40) * 32;
    const float* w = zi==0 ? w0 : zi==1 ? w1 : zi==2 ? w2 : w3;
    bf16*       o  = zi==0 ? o0 : zi==1 ? o1 : zi==2 ? o2 : o3;
    int tx = threadIdx.x & 31, ty = threadIdx.x >> 5;   // 32 x 8
    #pragma unroll
    for (int i = 0; i < 32; i += 8)
        t[ty+i][tx] = w[(size_t)(k0+ty+i)*C_DIM + n0 + tx];
    __syncthreads();
    #pragma unroll
    for (int i = 0; i < 32; i += 8)
        o[(size_t)(n0+ty+i)*C_DIM + k0 + tx] = (bf16)t[tx][ty+i];
}

// ------------- Fused QKV GEMM: 256x256 tile, BK=32, triple-buffered LDS,
// raw s_barrier + counted vmcnt, XOR-granule swizzle keyed by (row>>1)&3. -------------
#define QBM 256
#define QBN 256
#define QBK 32
#define QNT (C_DIM / QBK)   // 40
__global__ __launch_bounds__(512, 2) void k_gemm_qkv(
    const bf16* __restrict__ A,      // hs_bf [4096][1280]
    const bf16* __restrict__ Wcat,   // [3840][1280] = WqT|WkT|WvT
    bf16* __restrict__ Qo, bf16* __restrict__ Ko, bf16* __restrict__ VTo) {
    __shared__ bf16 lds[3][2][QBM][QBK];   // 96 KB
    const int m0  = blockIdx.y * QBM;
    const int nx  = blockIdx.x;            // 0..14
    const int z   = nx / 5;                // which weight
    const int nw0 = (nx % 5) * QBN;        // within-weight col base
    const int ng0 = nx * QBN;              // row into Wcat
    const int tid = threadIdx.x, lane = tid & 63, wid = tid >> 6;
    const int wm = wid >> 2, wn = wid & 3;
    const int g = lane >> 4, lr = lane & 15;
    const float scale = (z==0) ? 0.18033688011112042f : 1.0f;  // log2e/8 for Q

    f32x4 acc[8][4];
    #pragma unroll
    for (int i=0;i<8;i++)
        #pragma unroll
        for (int j=0;j<4;j++)
            acc[i][j] = zero4();

#define QSTAGE(bf, kt)                                                       \
    { const int k0_ = (kt)*QBK;                                              \
      _Pragma("unroll")                                                      \
      for (int c = 0; c < 2; ++c) {                                          \
        int p = c*512 + tid;                                                 \
        int row = p >> 2, gp = p & 3, gc = gp ^ ((row >> 1) & 3);            \
        async_copy16((char*)&lds[bf][0][0][0] + p*16,                        \
                     &A[(size_t)(m0+row)*C_DIM + k0_ + gc*8]);               \
        async_copy16((char*)&lds[bf][1][0][0] + p*16,                        \
                     &Wcat[(size_t)(ng0+row)*C_DIM + k0_ + gc*8]);           \
      } }

    QSTAGE(0, 0);
    QSTAGE(1, 1);
    asm volatile("s_waitcnt vmcnt(4)" ::: "memory");   // tile0 landed; tile1 in flight
    __builtin_amdgcn_s_barrier();

    int cur = 0;
    for (int t = 0; t < QNT; ++t) {
        if (t + 2 < QNT) {
            int sb = cur + 2; if (sb >= 3) sb -= 3;
            QSTAGE(sb, t + 2);                          // issue early, fly across barrier
        }
        const bf16* AB = &lds[cur][0][0][0];
        const bf16* BB = &lds[cur][1][0][0];
        bf16x8 af[8], bfr[4];
        #pragma unroll
        for (int mf = 0; mf < 8; ++mf) {
            int arow = wm*128 + mf*16 + lr;
            af[mf] = *(const bf16x8*)(AB + arow*QBK + ((g ^ ((arow >> 1) & 3)) << 3));
        }
        #pragma unroll
        for (int nf = 0; nf < 4; ++nf) {
            int brow = wn*64 + nf*16 + lr;
            bfr[nf] = *(const bf16x8*)(BB + brow*QBK + ((g ^ ((brow >> 1) & 3)) << 3));
        }
        #pragma unroll
        for (int mf = 0; mf < 8; ++mf)
            #pragma unroll
            for (int nf = 0; nf < 4; ++nf)
                acc[mf][nf] = __builtin_amdgcn_mfma_f32_16x16x32_bf16(
                    af[mf], bfr[nf], acc[mf][nf], 0,0,0);
        if (t + 2 < QNT) asm volatile("s_waitcnt vmcnt(4) lgkmcnt(0)" ::: "memory");
        else             asm volatile("s_waitcnt vmcnt(0) lgkmcnt(0)" ::: "memory");
        __builtin_amdgcn_s_barrier();
        if (++cur == 3) cur = 0;
    }

    if (z == 2) {
        // V: write directly transposed [B,H,D,S]
        #pragma unroll
        for (int mf=0;mf<8;mf++) {
            #pragma unroll
            for (int nf=0;nf<4;nf++) {
                int n = nw0 + wn*64 + nf*16 + lr;
                int h = n >> 6, d = n & 63;
                int m = m0 + wm*128 + mf*16 + g*4;
                int b = m >> 11, s = m & (S_LEN-1);
                bf16x4 ov;
                #pragma unroll
                for (int r=0;r<4;r++) ov[r] = (bf16)acc[mf][nf][r];
                *(bf16x4*)&VTo[((size_t)(b*H_NUM + h)*D_HEAD + d)*S_LEN + s] = ov;
            }
        }
    } else {
        bf16* Out = (z==0) ? Qo : Ko;
        #pragma unroll
        for (int mf=0;mf<8;mf++) {
            #pragma unroll
            for (int nf=0;nf<4;nf++) {
                int n = nw0 + wn*64 + nf*16 + lr;
                int h = n >> 6, d = n & 63;
                #pragma unroll
                for (int r=0;r<4;r++) {
                    int m = m0 + wm*128 + mf*16 + g*4 + r;
                    int b = m >> 11, s = m & (S_LEN-1);
                    Out[(size_t)((b*H_NUM + h)*S_LEN + s)*D_HEAD + d] = (bf16)(acc[mf][nf][r] * scale);
                }
            }
        }
    }
}

// ------------- output GEMM (128x128, BK=64, swizzled, dbuf early-issue)
// + folded deterministic loss reduce (block (0,0) only). -------------
#define BM 128
#define BN 128
#define BK 64

#define GEMM_STAGE(Al, Bl, Aptr, Bptr, m0, n0, k0)                                \
    {                                                                             \
        _Pragma("unroll")                                                         \
        for (int c = 0; c < 4; ++c) {                                             \
            int p = c*256 + tid;                                                  \
            int row = p >> 3, gp = p & 7, gc = gp ^ (row & 7);                    \
            async_copy16((char*)(Al) + p*16,                                      \
                         &Aptr[(size_t)((m0)+row)*C_DIM + (k0) + gc*8]);          \
            async_copy16((char*)(Bl) + p*16,                                      \
                         &Bptr[(size_t)((n0)+row)*C_DIM + (k0) + gc*8]);          \
        }                                                                         \
    }

#define GEMM_COMPUTE(Al, Bl)                                                      \
    {                                                                             \
        _Pragma("unroll")                                                         \
        for (int kk = 0; kk < 2; ++kk) {                                          \
            bf16x8 af[4], bfr[4];                                                 \
            _Pragma("unroll")                                                     \
            for (int mf = 0; mf < 4; ++mf) {                                      \
                int arow = wm*64 + mf*16 + lr;                                    \
                af[mf] = *(const bf16x8*)((char*)(Al) + arow*128 +                \
                          (((kk*4 + g) ^ (arow & 7)) << 4));                      \
            }                                                                     \
            _Pragma("unroll")                                                     \
            for (int nf = 0; nf < 4; ++nf) {                                      \
                int brow = wn*64 + nf*16 + lr;                                    \
                bfr[nf] = *(const bf16x8*)((char*)(Bl) + brow*128 +               \
                          (((kk*4 + g) ^ (brow & 7)) << 4));                      \
            }                                                                     \
            _Pragma("unroll")                                                     \
            for (int mf = 0; mf < 4; ++mf)                                        \
                _Pragma("unroll")                                                 \
                for (int nf = 0; nf < 4; ++nf)                                    \
                    acc[mf][nf] = __builtin_amdgcn_mfma_f32_16x16x32_bf16(        \
                        af[mf], bfr[nf], acc[mf][nf], 0,0,0);                     \
        }                                                                         \
    }

__global__ __launch_bounds__(256) void k_gemm_out(
    const bf16* __restrict__ A,                     // Oattn [4096][1280]
    const bf16* __restrict__ WoT,
    const float* __restrict__ bo,
    const float* __restrict__ res,                  // hidden_states fp32
    float* __restrict__ out,
    const float* __restrict__ lossPart, int nLoss) {
    __shared__ bf16 Al[2][BM][BK];
    __shared__ bf16 Bl[2][BN][BK];
    __shared__ float wred[4];
    const int m0 = blockIdx.y * BM, n0 = blockIdx.x * BN;
    const int tid = threadIdx.x, lane = tid & 63, wid = tid >> 6;
    const int wm = wid >> 1, wn = wid & 1;
    const int g = lane >> 4, lr = lane & 15;
    f32x4 acc[4][4];
    #pragma unroll
    for (int i=0;i<4;i++)
        #pragma unroll
        for (int j=0;j<4;j++)
            acc[i][j] = zero4();
    GEMM_STAGE(&Al[0][0][0], &Bl[0][0][0], A, WoT, m0, n0, 0);
    asm volatile("s_waitcnt vmcnt(0)" ::: "memory");
    __builtin_amdgcn_s_barrier();
    int cur = 0;
    for (int k0 = 0; k0 < C_DIM; k0 += BK) {
        if (k0 + BK < C_DIM)
            GEMM_STAGE(&Al[cur^1][0][0], &Bl[cur^1][0][0], A, WoT, m0, n0, k0 + BK);
        GEMM_COMPUTE(&Al[cur][0][0], &Bl[cur][0][0]);
        asm volatile("s_waitcnt vmcnt(0) lgkmcnt(0)" ::: "memory");
        __builtin_amdgcn_s_barrier();
        cur ^= 1;
    }
    #pragma unroll
    for (int mf=0;mf<4;mf++) {
        #pragma unroll
        for (int nf=0;nf<4;nf++) {
            int n = n0 + wn*64 + nf*16 + lr;
            float bias = bo[n];
            #pragma unroll
            for (int r=0;r<4;r++) {
                int m = m0 + wm*64 + mf*16 + g*4 + r;
                size_t idx = (size_t)m*C_DIM + n;
                out[idx] = acc[mf][nf][r] + bias + res[idx];
            }
        }
    }
    // folded loss reduce: lossPart was fully written by k_attn (prior launch)
    if (blockIdx.x == 0 && blockIdx.y == 0) {
        float s = 0.f;
        for (int i = tid; i < nLoss; i += 256) s += lossPart[i];
        #pragma unroll
        for (int msk=1; msk<64; msk<<=1) s += __shfl_xor(s, msk);
        if (lane == 0) wred[wid] = s;
        __syncthreads();
        if (tid == 0) out[(size_t)M_TOT*C_DIM] = sqrtf(wred[0]+wred[1]+wred[2]+wred[3]);
    }
}

// ------------- flash attention + loss partials (R18-proven) -------------
// Swapped-operand flash attn; 512-thread blocks (8 waves, 128 q rows),
// grid 640. TRIPLE-buffered K/V (48 KB) + raw s_barrier + counted vmcnt(2).
// Q pre-scaled by log2e/8 -> raw v_exp_f32. l via ones-MFMA; s2 via
// mfma(pb,pb) diag. XCD swizzle: 640 = 8 x 80 -> K/V L2-resident.
#define KVB 64
#define NT_ (S_LEN / KVB)   // 32
__global__ __launch_bounds__(512) void k_attn(
    const bf16* __restrict__ Q,    // [B,H,S,D], pre-scaled by log2e/8
    const bf16* __restrict__ Kg,   // [B,H,S,D]
    const bf16* __restrict__ VT,   // [B,H,D,S]
    bf16* __restrict__ O,          // [B,S,H,D]
    float* __restrict__ lossPart) {
    __shared__ bf16 Kl[3][KVB][64];
    __shared__ bf16 Vl[3][D_HEAD][64];   // 48 KB

    const int id  = blockIdx.x;              // 0..639
    const int fid = (id & 7) * 80 + (id >> 3);   // XCD-contiguous (640%8==0)
    const int bh = fid >> 4;                 // 0..39 (5 whole heads per XCD)
    const int qb = fid & 15;                 // 0..15 (128 q rows per block)
    const int b = bh / H_NUM, hh = bh % H_NUM;
    const int tid = threadIdx.x, lane = tid & 63, wid = tid >> 6;  // wid 0..7
    const int g = lane >> 4, lr = lane & 15;

    const bf16* Kbase = Kg + (size_t)bh * S_LEN * D_HEAD;
    const bf16* Vbase = VT + (size_t)bh * D_HEAD * S_LEN;

    // per-lane q row (each of the 8 waves owns a 16-row strip)
    const int qrow = qb*128 + wid*16 + lr;
    const bf16* qp = Q + ((size_t)bh*S_LEN + qrow)*D_HEAD;
    const bf16x8 aq0 = *(const bf16x8*)(qp + g*8);        // Q^T B-frag, d-half 0
    const bf16x8 aq1 = *(const bf16x8*)(qp + 32 + g*8);   // d-half 1

    // ones A-fragment for the l-MFMA
    bf16x8 ones;
    #pragma unroll
    for (int i=0;i<8;i++) ones[i] = (bf16)1.0f;

    // K LDS read-row components (phys kv -> LDS row sigma: swap bits 2,3)
    const int lb7 = (lr & 3) | (((lr >> 2) & 1) << 2);    // LDS row bits 0..2
    const int lhi = ((lr >> 2) & 2) << 3;                 // LDS row bit 4

    f32x4 o_acc[4];
    #pragma unroll
    for (int i=0;i<4;i++) o_acc[i] = zero4();
    f32x4 l_acc = zero4();
    f32x4 s2m   = zero4();

// 512 threads cover the 512 K granules (and 512 V granules): 2 vmem ops/thread.
#define STAGE(buf, kv0)                                                          \
    {                                                                            \
        {                                                                        \
            int p = tid;                                                         \
            int lrow = p >> 3, gp = p & 7;                                       \
            int tl = (lrow & 51) | ((lrow & 4) << 1) | ((lrow & 8) >> 1);        \
            async_copy16((char*)&Kl[buf][0][0] + p*16,                           \
                         Kbase + (size_t)((kv0) + tl)*D_HEAD                     \
                               + ((gp ^ (lrow & 7)) << 3));                      \
        }                                                                        \
        {                                                                        \
            int p = tid;                                                         \
            int drow = p >> 3, gp = p & 7;                                       \
            async_copy16((char*)&Vl[buf][0][0] + p*16,                           \
                         Vbase + (size_t)drow*S_LEN + (kv0)                      \
                               + ((gp ^ (drow & 7)) << 3));                      \
        }                                                                        \
    }

    STAGE(0, 0);
    STAGE(1, KVB);
    asm volatile("s_waitcnt vmcnt(2)" ::: "memory");   // tile0 landed; tile1 in flight
    __builtin_amdgcn_s_barrier();

    int cur = 0;
    for (int t = 0; t < NT_; ++t) {
        if (t + 2 < NT_) {
            int sb = cur + 2; if (sb >= 3) sb -= 3;
            STAGE(sb, (t+2)*KVB);                       // fly across the barrier
        }
        const bf16* KB = &Kl[cur][0][0];
        const bf16* VB = &Vl[cur][0][0];

        // QK^T (swapped): acc_p[pair][u][r] = S^T[kv = pair*32+g*8+u*4+r][q=qrow]
        f32x4 accp[2][2];
        __builtin_amdgcn_s_setprio(1);
        #pragma unroll
        for (int pair=0; pair<2; ++pair)
            #pragma unroll
            for (int u=0; u<2; ++u) {
                const bf16* kr = KB + (pair*32 + (u<<3) + lhi + lb7)*64;
                bf16x8 k0 = *(const bf16x8*)(kr + ((g       ^ lb7) << 3));
                bf16x8 k1 = *(const bf16x8*)(kr + (((4 + g) ^ lb7) << 3));
                f32x4 c = zero4();
                c = __builtin_amdgcn_mfma_f32_16x16x32_bf16(k0, aq0, c, 0,0,0);
                c = __builtin_amdgcn_mfma_f32_16x16x32_bf16(k1, aq1, c, 0,0,0);
                accp[pair][u] = c;
            }
        __builtin_amdgcn_s_setprio(0);
        // unnormalized p = 2^(s'): single v_exp_f32 each, lane-local
        bf16x8 pb[2];
        #pragma unroll
        for (int pair=0; pair<2; ++pair)
            #pragma unroll
            for (int u=0; u<2; ++u)
                #pragma unroll
                for (int r=0; r<4; ++r) {
                    float e = __builtin_amdgcn_exp2f(accp[pair][u][r]);
                    pb[pair][u*4+r] = (bf16)e;
                }
        __builtin_amdgcn_s_setprio(1);
        // l via MFMA (A=ones): fully k-reduced Sum(p) per q column
        l_acc = __builtin_amdgcn_mfma_f32_16x16x32_bf16(ones, pb[0], l_acc, 0,0,0);
        l_acc = __builtin_amdgcn_mfma_f32_16x16x32_bf16(ones, pb[1], l_acc, 0,0,0);
        // s2 via MFMA: (P^T P); diagonal = Sum(p^2) per q
        s2m = __builtin_amdgcn_mfma_f32_16x16x32_bf16(pb[0], pb[0], s2m, 0,0,0);
        s2m = __builtin_amdgcn_mfma_f32_16x16x32_bf16(pb[1], pb[1], s2m, 0,0,0);
        // PV: O^T += V^T . P^T
        #pragma unroll
        for (int ds_=0; ds_<4; ++ds_) {
            const bf16* vr = VB + (ds_*16 + lr)*64;
            #pragma unroll
            for (int pair=0; pair<2; ++pair) {
                bf16x8 v = *(const bf16x8*)(vr + (((pair*4 + g) ^ (lr & 7)) << 3));
                o_acc[ds_] = __builtin_amdgcn_mfma_f32_16x16x32_bf16(v, pb[pair], o_acc[ds_], 0,0,0);
            }
        }
        __builtin_amdgcn_s_setprio(0);
        // tile t+1's loads done (oldest 2 of 4 outstanding); t+2's fly on.
        if (t + 2 < NT_) asm volatile("s_waitcnt vmcnt(2) lgkmcnt(0)" ::: "memory");
        else             asm volatile("s_waitcnt vmcnt(0) lgkmcnt(0)" ::: "memory");
        __builtin_amdgcn_s_barrier();
        if (++cur == 3) cur = 0;
    }

    // l is complete per q column (MFMA sums all k)
    const float lfull = l_acc[0];

    // O write: lane owns q=qrow, holds O^T[d = ds_*16+g*4+r]
    const float inv = 1.0f / lfull;
    bf16* orow = O + ((size_t)(b*S_LEN + qrow)*H_NUM + hh)*D_HEAD;
    #pragma unroll
    for (int ds_=0; ds_<4; ++ds_) {
        bf16x4 ov;
        #pragma unroll
        for (int r=0; r<4; ++r) ov[r] = (bf16)(o_acc[ds_][r] * inv);
        *(bf16x4*)(orow + ds_*16 + g*4) = ov;
    }
    // loss partial: diag of s2m holds Sum(p^2) for q=lr on the lane with
    // g == lr>>2 (row==col), element lr&3. One lane per q -> no /4.
    float v = 0.f;
    if (g == (lr >> 2)) v = s2m[lr & 3] / (lfull * lfull);
    #pragma unroll
    for (int msk=1; msk<64; msk<<=1) v += __shfl_xor(v, msk);
    if (lane == 0) lossPart[(bh*16 + qb)*8 + wid] = v;
}

extern "C" void kernel_launch(void* const* d_in, const int* in_sizes, int n_in,
                              void* d_out, int out_size, void* d_ws, size_t ws_size,
                              hipStream_t stream) {
    (void)in_sizes; (void)n_in; (void)out_size; (void)ws_size;
    const float* hs = (const float*)d_in[0];
    const float* Wq = (const float*)d_in[1];
    const float* Wk = (const float*)d_in[2];
    const float* Wv = (const float*)d_in[3];
    const float* Wo = (const float*)d_in[4];
    const float* bo = (const float*)d_in[5];
    float* out = (float*)d_out;

    constexpr size_t HS_E = (size_t)M_TOT * C_DIM;       // 5,242,880
    constexpr size_t W_E  = (size_t)C_DIM * C_DIM;       // 1,638,400
    char* ws = (char*)d_ws;
    size_t off = 0;
    bf16* hs_bf = (bf16*)(ws + off); off += HS_E * 2;
    bf16* WqT   = (bf16*)(ws + off); off += W_E * 2;     // WqT|WkT|WvT contiguous
    bf16* WkT   = (bf16*)(ws + off); off += W_E * 2;
    bf16* WvT   = (bf16*)(ws + off); off += W_E * 2;
    bf16* WoT   = (bf16*)(ws + off); off += W_E * 2;
    bf16* Qb    = (bf16*)(ws + off); off += HS_E * 2;
    bf16* Kb    = (bf16*)(ws + off); off += HS_E * 2;
    bf16* Vtb   = (bf16*)(ws + off); off += HS_E * 2;    // V^T [B,H,D,S], written by gemm
    bf16* Ob    = (bf16*)(ws + off); off += HS_E * 2;
    float* lossPart = (float*)(ws + off); off += 5120 * 4;

    k_prep<<<11520, 256, 0, stream>>>(hs, hs_bf, Wq, Wk, Wv, Wo, WqT, WkT, WvT, WoT);
    k_gemm_qkv<<<dim3(3*C_DIM/QBN, M_TOT/QBM), 512, 0, stream>>>(hs_bf, WqT, Qb, Kb, Vtb);
    k_attn<<<640, 512, 0, stream>>>(Qb, Kb, Vtb, Ob, lossPart);
    k_gemm_out<<<dim3(C_DIM/BN, M_TOT/BM), 256, 0, stream>>>(Ob, WoT, bo, hs, out, lossPart, 5120);
}